// Round 8
// baseline (257.088 us; speedup 1.0000x reference)
//
#include <hip/hip_runtime.h>
#include <stdint.h>

#define B_ 4
#define D_ 256
#define N_ 4096
#define K_ 8192
#define Q_ (B_*N_)   // 16384 queries

#define KSPLIT_ 4            // K-split
#define KSLICE_ (K_/KSPLIT_) // 2048 codes per block
#define CHUNK_ 64            // codes per chunk (2 x 32-code MFMA sub-tiles)
#define NCHUNK_ (KSLICE_/CHUNK_) // 32 chunks
#define QTILE_ 256           // queries per block (8 waves x 32)

typedef __attribute__((ext_vector_type(8))) short bf16x8;
typedef __attribute__((ext_vector_type(16))) float f32x16;

__device__ __forceinline__ unsigned short f32_to_bf16(float f) {
  unsigned u = __float_as_uint(f);
  unsigned r = 0x7FFFu + ((u >> 16) & 1u);
  return (unsigned short)((u + r) >> 16);
}
__device__ __forceinline__ float bf16_to_f32(unsigned short h) {
  return __uint_as_float(((unsigned)h) << 16);
}

// async global->LDS, 16B per lane; LDS dest is wave-uniform base + lane*16
__device__ __forceinline__ void gl_lds16(const void* g, void* l) {
  __builtin_amdgcn_global_load_lds(
      (const __attribute__((address_space(1))) unsigned int*)g,
      (__attribute__((address_space(3))) unsigned int*)l, 16, 0, 0);
}

// Transpose x [B, D, N] -> xh/xl [Q=B*N, D] bf16 hi/lo split.
__global__ void prep_x_kernel(const float* __restrict__ x,
                              unsigned short* __restrict__ xh,
                              unsigned short* __restrict__ xl) {
  __shared__ float tile[32][33];
  int b = blockIdx.z;
  int d0 = blockIdx.y * 32;
  int n0 = blockIdx.x * 32;
  int tx = threadIdx.x, ty = threadIdx.y;
  const float* xp = x + ((size_t)b * D_ + d0) * N_ + n0;
#pragma unroll
  for (int i = 0; i < 4; ++i)
    tile[ty + 8 * i][tx] = xp[(size_t)(ty + 8 * i) * N_ + tx];
  __syncthreads();
#pragma unroll
  for (int i = 0; i < 4; ++i) {
    int nl = ty + 8 * i;
    float v = tile[tx][nl];
    unsigned short h = f32_to_bf16(v);
    unsigned short l = f32_to_bf16(v - bf16_to_f32(h));
    size_t q = (size_t)b * N_ + n0 + nl;
    xh[q * D_ + d0 + tx] = h;
    xl[q * D_ + d0 + tx] = l;
  }
}

// Split e [K, D] into bf16 hi/lo; compute 0.5*||e_k||^2; init keys.
__global__ void prep_e_kernel(const float* __restrict__ e,
                              unsigned short* __restrict__ eh,
                              unsigned short* __restrict__ el,
                              float* __restrict__ e2h,
                              unsigned long long* __restrict__ keys) {
  int k = blockIdx.x;
  int d = threadIdx.x;  // 256 threads
  if (d < 2) keys[(size_t)k * 2 + d] = ~0ull;  // Q_ = 2*K_
  float v = e[(size_t)k * D_ + d];
  unsigned short h = f32_to_bf16(v);
  unsigned short l = f32_to_bf16(v - bf16_to_f32(h));
  eh[(size_t)k * D_ + d] = h;
  el[(size_t)k * D_ + d] = l;
  float s = v * v;
#pragma unroll
  for (int off = 32; off > 0; off >>= 1) s += __shfl_down(s, off, 64);
  __shared__ float ws4[4];
  if ((threadIdx.x & 63) == 0) ws4[threadIdx.x >> 6] = s;
  __syncthreads();
  if (threadIdx.x == 0) e2h[k] = 0.5f * (ws4[0] + ws4[1] + ws4[2] + ws4[3]);
}

// Main R8: R7 frame (CHUNK=64, 8 waves x 32 q, 2/SIMD) + EXPLICIT DEPTH-2
// B-READ SOFTWARE PIPELINE. Unified theory from R0-R7 (MfmaUtil pinned at
// ~52% under barrier/chain/vmcnt/tile changes): hipcc emits just-in-time
// ds_reads with zero read-ahead, so every 3-MFMA triple pays the full
// ~150-200 cyc LDS round trip, covered only by 96 own + 96 partner MFMA
// cyc -> ~50% starve. Fix: SSA cur/nxt rotation issues reads for iter kk+2
// BEFORE the MFMAs of kk (static names, full unroll — rule #20).
// Register diet to make room: R0 epilogue (dv = e2 - acc), rmini packed as
// 8-bit chunk-codes in 4 VGPRs (kidx = kbase + code*32 + l reconstructible,
// l is thread-constant), fused 32-iter loop (1 pipeline bubble per chunk).
__global__ __launch_bounds__(512, 2) void vq_main_kernel(
    const unsigned short* __restrict__ xh, const unsigned short* __restrict__ xl,
    const unsigned short* __restrict__ eh, const unsigned short* __restrict__ el,
    const float* __restrict__ e2h, unsigned long long* __restrict__ keys) {
  // [buf][half][code*256 + swizzled runs]; 128 KB total, dense (DMA-ok).
  // 16B-slot s of code row c holds run g = s ^ (c&31).
  __shared__ __attribute__((aligned(16))) unsigned short Bs[2][2][CHUNK_ * 256];

  const int tid = threadIdx.x;
  const int w = tid >> 6;       // wave 0..7
  const int lane = tid & 63;
  const int l = lane & 31;      // spatial index (code col / query row)
  const int hi = lane >> 5;     // k-group half

  const int qt = blockIdx.x >> 2;
  const int ksl = blockIdx.x & 3;
  const int q0 = qt * QTILE_;
  const int kbase = ksl * KSLICE_;
  const int qw = q0 + w * 32;

  // Persistent A fragments: 32 queries x 256 d, hi+lo.
  // A[m=lane&31][k=hi*8+j]; 128 regs, allocator places in AGPRs.
  bf16x8 ah[16], al[16];
  {
    const unsigned short* pa = xh + (size_t)(qw + l) * D_ + hi * 8;
    const unsigned short* pb = xl + (size_t)(qw + l) * D_ + hi * 8;
#pragma unroll
    for (int kc16 = 0; kc16 < 16; ++kc16) {
      ah[kc16] = *(const bf16x8*)(pa + kc16 * 16);
      al[kc16] = *(const bf16x8*)(pb + kc16 * 16);
    }
  }

  float rminv[16];
  unsigned rmp[4];  // 16 x 8-bit packed chunk-subtile codes (vc = ch*2+st)
#pragma unroll
  for (int r = 0; r < 16; ++r) rminv[r] = __builtin_inff();
#pragma unroll
  for (int i = 0; i < 4; ++i) rmp[i] = 0u;

  // Stage chunk ch (64 codes x hi/lo) into buf: wave w loads codes
  // [w*8, w*8+8). One instr = 64 lanes x 16B = 2 code rows, swizzled via
  // source address. 8 gl_lds per wave per chunk.
  auto stage = [&](int ch, int buf) {
    const int kc = kbase + ch * CHUNK_;
#pragma unroll
    for (int p = 0; p < 4; ++p) {
      const int c0 = w * 8 + p * 2;
      const int c = c0 + hi;
      const int g = l ^ (c & 31);
      const size_t srcoff = (size_t)(kc + c) * D_ + g * 8;
      gl_lds16(eh + srcoff, &Bs[buf][0][c0 * 256]);
      gl_lds16(el + srcoff, &Bs[buf][1][c0 * 256]);
    }
  };

  stage(0, 0);

#pragma unroll 1
  for (int ch = 0; ch < NCHUNK_; ++ch) {
    const int buf = ch & 1;
    __syncthreads();                    // drains DMA for chunk ch
    if (ch + 1 < NCHUNK_) stage(ch + 1, buf ^ 1);
    const int kc = kbase + ch * CHUNK_;
    const float e2v0 = e2h[kc + l];       // in flight under first iters
    const float e2v1 = e2h[kc + 32 + l];

    const unsigned short* bh_base = &Bs[buf][0][0];
    const unsigned short* bl_base = &Bs[buf][1][0];
    // read for fused iter kk: subtile st=kk>>4 (row 32*st+l), ks=kk&15
#define RD(base, kk) \
    (*(const bf16x8*)&(base)[(((kk) >> 4) * 32 + l) * 256 + \
                             (((((kk) & 15) * 2 + hi) ^ l) * 8)])

    f32x16 acc0, acc1;
#pragma unroll
    for (int r = 0; r < 16; ++r) { acc0[r] = 0.f; acc1[r] = 0.f; }

    // depth-2 software pipeline: reads for kk+2 issue before MFMAs of kk
    bf16x8 cbh = RD(bh_base, 0), cbl = RD(bl_base, 0);
    bf16x8 nbh = RD(bh_base, 1), nbl = RD(bl_base, 1);
#pragma unroll
    for (int kk = 0; kk < 32; ++kk) {
      const bf16x8 ubh = cbh, ubl = cbl;
      cbh = nbh; cbl = nbl;
      if (kk + 2 < 32) { nbh = RD(bh_base, kk + 2); nbl = RD(bl_base, kk + 2); }
      const int ks = kk & 15;
      if (kk < 16) {
        acc0 = __builtin_amdgcn_mfma_f32_32x32x16_bf16(ah[ks], ubh, acc0, 0, 0, 0);
        acc0 = __builtin_amdgcn_mfma_f32_32x32x16_bf16(ah[ks], ubl, acc0, 0, 0, 0);
        acc0 = __builtin_amdgcn_mfma_f32_32x32x16_bf16(al[ks], ubh, acc0, 0, 0, 0);
      } else {
        acc1 = __builtin_amdgcn_mfma_f32_32x32x16_bf16(ah[ks], ubh, acc1, 0, 0, 0);
        acc1 = __builtin_amdgcn_mfma_f32_32x32x16_bf16(ah[ks], ubl, acc1, 0, 0, 0);
        acc1 = __builtin_amdgcn_mfma_f32_32x32x16_bf16(al[ks], ubh, acc1, 0, 0, 0);
      }
      if (kk == 15) {  // retire subtile 0 (frees acc0 pressure early)
        const unsigned vc = (unsigned)(ch * 2 + 0);
#pragma unroll
        for (int r = 0; r < 16; ++r) {
          float dv = e2v0 - acc0[r];
          bool better = dv < rminv[r];
          rminv[r] = better ? dv : rminv[r];
          const unsigned sh = (r & 3) * 8;
          unsigned np = (rmp[r >> 2] & ~(0xFFu << sh)) | (vc << sh);
          rmp[r >> 2] = better ? np : rmp[r >> 2];
        }
      }
    }
#undef RD
    {  // retire subtile 1
      const unsigned vc = (unsigned)(ch * 2 + 1);
#pragma unroll
      for (int r = 0; r < 16; ++r) {
        float dv = e2v1 - acc1[r];
        bool better = dv < rminv[r];
        rminv[r] = better ? dv : rminv[r];
        const unsigned sh = (r & 3) * 8;
        unsigned np = (rmp[r >> 2] & ~(0xFFu << sh)) | (vc << sh);
        rmp[r >> 2] = better ? np : rmp[r >> 2];
      }
    }
  }

  // Reduce over the 32 code-columns within each half-wave, then cross-block
  // merge via packed (sortable-float<<32 | idx) u64 atomicMin.
#pragma unroll
  for (int r = 0; r < 16; ++r) {
    float bv = rminv[r];
    const unsigned sh = (r & 3) * 8;
    int bi = kbase + (int)((rmp[r >> 2] >> sh) & 0xFFu) * 32 + l;
#pragma unroll
    for (int xm = 1; xm <= 16; xm <<= 1) {
      float ov = __shfl_xor(bv, xm, 64);
      int oi = __shfl_xor(bi, xm, 64);
      if (ov < bv || (ov == bv && oi < bi)) { bv = ov; bi = oi; }
    }
    if (l == 0) {
      const int m = (r & 3) + 8 * (r >> 2) + 4 * hi;  // C/D row mapping (m74/m101)
      const int qq = qw + m;
      unsigned su = __float_as_uint(bv);
      su ^= (unsigned)(((int)su >> 31) | 0x80000000u);
      unsigned long long key = ((unsigned long long)su << 32) | (unsigned)bi;
      atomicMin(keys + qq, key);
    }
  }
}

// Decode: out[b][d][n] = e[code[b,n]][d].
// Tiled LDS-transpose gather: reads e rows in coalesced 128B slices,
// writes out in 128B-contiguous n-runs.
__global__ void decode_kernel(const unsigned long long* __restrict__ keys,
                              const float* __restrict__ e,
                              float* __restrict__ out) {
  __shared__ float tile[32][33];
  __shared__ int codes[32];
  int b = blockIdx.y;
  int n0 = blockIdx.x * 32;
  int tx = threadIdx.x, ty = threadIdx.y;  // (32, 8)
  if (ty == 0)
    codes[tx] = (int)(keys[(size_t)b * N_ + n0 + tx] & 0xFFFFFFFFull);
  __syncthreads();
#pragma unroll 1
  for (int d0 = 0; d0 < D_; d0 += 32) {
    // gather: row nl's 32-d slice, coalesced 128B per row
#pragma unroll
    for (int i = 0; i < 4; ++i) {
      int nl = ty + 8 * i;
      tile[nl][tx] = e[(size_t)codes[nl] * D_ + d0 + tx];
    }
    __syncthreads();
    // transposed write: 32 consecutive n per instruction
#pragma unroll
    for (int i = 0; i < 4; ++i) {
      int dl = ty + 8 * i;
      out[((size_t)b * D_ + d0 + dl) * N_ + n0 + tx] = tile[tx][dl];
    }
    __syncthreads();
  }
}

extern "C" void kernel_launch(void* const* d_in, const int* in_sizes, int n_in,
                              void* d_out, int out_size, void* d_ws, size_t ws_size,
                              hipStream_t stream) {
  const float* x = (const float*)d_in[0];
  const float* e = (const float*)d_in[1];
  float* out = (float*)d_out;

  // workspace layout (~24.2 MB)
  char* wksp = (char*)d_ws;
  unsigned short* xh = (unsigned short*)wksp;                   // 8 MB
  unsigned short* xl = xh + (size_t)Q_ * D_;                    // 8 MB
  unsigned short* eh = xl + (size_t)Q_ * D_;                    // 4 MB
  unsigned short* el = eh + (size_t)K_ * D_;                    // 4 MB
  float* e2h = (float*)(el + (size_t)K_ * D_);                  // 32 KB
  unsigned long long* keys = (unsigned long long*)(e2h + K_);   // 128 KB

  prep_x_kernel<<<dim3(N_ / 32, D_ / 32, B_), dim3(32, 8), 0, stream>>>(x, xh, xl);
  prep_e_kernel<<<K_, 256, 0, stream>>>(e, eh, el, e2h, keys);
  vq_main_kernel<<<(Q_ / QTILE_) * KSPLIT_, 512, 0, stream>>>(xh, xl, eh, el, e2h, keys);
  decode_kernel<<<dim3(N_ / 32, B_), dim3(32, 8), 0, stream>>>(keys, e, out);
}